// Round 1
// baseline (550.420 us; speedup 1.0000x reference)
//
#include <hip/hip_runtime.h>

typedef short bf16x8 __attribute__((ext_vector_type(8)));
typedef float f32x4 __attribute__((ext_vector_type(4)));

#define LDP 136   // padded stride (bf16 elems) for 128-wide LDS tiles: 272B rows -> 2-way bank alias (free)
#define LDX 40    // padded stride for the 32-wide x tile (80B rows, 16B-aligned)
#define NEG 0.01f

__device__ __forceinline__ unsigned short f2bf(float f) {
  union { float f; unsigned u; } v; v.f = f;
  unsigned u = v.u;
  return (unsigned short)((u + 0x7fffu + ((u >> 16) & 1u)) >> 16);
}
__device__ __forceinline__ float bflo(unsigned u) { return __uint_as_float(u << 16); }
__device__ __forceinline__ float bfhi(unsigned u) { return __uint_as_float(u & 0xffff0000u); }

__device__ __forceinline__ float lrelu(float v) {
  return fmaxf(v, 0.0f) + NEG * fminf(v, 0.0f);
}
__device__ __forceinline__ float tanh_fast(float x) {
  float e = __expf(2.0f * x);
  return 1.0f - __fdividef(2.0f, e + 1.0f);
}

// Stage a [rows x COLS] f32 weight (row stride gld) -> bf16 LDS tile (row stride lds)
template<int COLS>
__device__ __forceinline__ void stage_w(const float* __restrict__ g, int gld,
                                        unsigned short* s, int lds, int rows, int tid) {
  const int perRow = COLS / 4;
  const int total = rows * perRow;
  for (int i = tid; i < total; i += 256) {
    int r = i / perRow, q = i - r * perRow;
    float4 v = *(const float4*)(g + r * gld + q * 4);
    ushort4 o; o.x = f2bf(v.x); o.y = f2bf(v.y); o.z = f2bf(v.z); o.w = f2bf(v.w);
    *(ushort4*)(s + r * lds + q * 4) = o;
  }
}

template<int NF>
__device__ __forceinline__ void zero_acc(f32x4 acc[4][NF]) {
  #pragma unroll
  for (int m = 0; m < 4; ++m)
    #pragma unroll
    for (int n = 0; n < NF; ++n) {
      f32x4 z = {0.f, 0.f, 0.f, 0.f};
      acc[m][n] = z;
    }
}

// Wave-cooperative GEMM: out rows [rowBase, rowBase+64) x cols [colBase, colBase+16*NF)
// A: act LDS tile (stride LDA), row = node, col = k.  B: weight LDS tile (stride LDP), row = out_ch, col = k.
// out[n][c] = sum_k A[n][k] * W[c][k]; accumulates into acc.
template<int NF, int KSTEPS, int LDA>
__device__ __forceinline__ void wave_gemm(const unsigned short* aS, const unsigned short* wS,
                                          int rowBase, int colBase, f32x4 acc[4][NF], int lane) {
  const int l15 = lane & 15, lg = lane >> 4;
  #pragma unroll
  for (int ks = 0; ks < KSTEPS; ++ks) {
    const int k = ks * 32 + lg * 8;
    bf16x8 a[4], b[NF];
    #pragma unroll
    for (int mf = 0; mf < 4; ++mf)
      a[mf] = *(const bf16x8*)(aS + (rowBase + 16 * mf + l15) * LDA + k);
    #pragma unroll
    for (int nf = 0; nf < NF; ++nf)
      b[nf] = *(const bf16x8*)(wS + (colBase + 16 * nf + l15) * LDP + k);
    #pragma unroll
    for (int mf = 0; mf < 4; ++mf)
      #pragma unroll
      for (int nf = 0; nf < NF; ++nf)
        acc[mf][nf] = __builtin_amdgcn_mfma_f32_16x16x32_bf16(a[mf], b[nf], acc[mf][nf], 0, 0, 0);
  }
}

// Apply bias+activation to acc and write bf16 into aS (in-place layer update).
template<int ACT>  // 0 = lrelu, 1 = tanh
__device__ __forceinline__ void write_act_lds(f32x4 acc[4][4], const float* __restrict__ bias,
                                              unsigned short* aS, int rowBase, int colBase,
                                              int l15, int lg) {
  #pragma unroll
  for (int nf = 0; nf < 4; ++nf) {
    int col = colBase + 16 * nf + l15;
    float bv = bias[col];
    #pragma unroll
    for (int mf = 0; mf < 4; ++mf)
      #pragma unroll
      for (int i = 0; i < 4; ++i) {
        int row = rowBase + 16 * mf + 4 * lg + i;
        float v = acc[mf][nf][i] + bv;
        v = (ACT == 0) ? lrelu(v) : tanh_fast(v);
        aS[row * LDP + col] = f2bf(v);
      }
  }
}

// ---------------- Kernel 1: prep MLP.  x[N,16] -> h (bf16) and z0 (f32, init = h) ----------------
extern "C" __global__ void __launch_bounds__(256, 2) prep_kernel(
    const float* __restrict__ x,
    const float* __restrict__ w0, const float* __restrict__ b0,
    const float* __restrict__ w1, const float* __restrict__ b1,
    unsigned short* hB, float* __restrict__ z0, int N) {
  __shared__ unsigned short xS[128 * LDX];
  __shared__ unsigned short aS[128 * LDP];
  __shared__ unsigned short wS[128 * LDP];
  const int tid = threadIdx.x, lane = tid & 63, wave = tid >> 6;
  const int l15 = lane & 15, lg = lane >> 4;
  const int wr = wave >> 1, wc = wave & 1;
  const int rowBase = 64 * wr, colBase = 64 * wc;
  const int nb = blockIdx.x * 128;

  // stage x tile (zero-padded k=16..31 for the K=32 MFMA)
  for (int i = tid; i < 128 * 4; i += 256) {
    int r = i >> 2, q = i & 3;
    int node = nb + r; node = node < N ? node : N - 1;
    float4 v = *(const float4*)(x + node * 16 + q * 4);
    ushort4 o; o.x = f2bf(v.x); o.y = f2bf(v.y); o.z = f2bf(v.z); o.w = f2bf(v.w);
    *(ushort4*)(xS + r * LDX + q * 4) = o;
    ushort4 zz; zz.x = 0; zz.y = 0; zz.z = 0; zz.w = 0;
    *(ushort4*)(xS + r * LDX + 16 + q * 4) = zz;
  }
  stage_w<16>(w0, 16, wS, LDP, 128, tid);
  for (int i = tid; i < 128 * 4; i += 256) {
    int r = i >> 2, q = i & 3;
    ushort4 zz; zz.x = 0; zz.y = 0; zz.z = 0; zz.w = 0;
    *(ushort4*)(wS + r * LDP + 16 + q * 4) = zz;
  }
  __syncthreads();

  f32x4 acc[4][4];
  zero_acc<4>(acc);
  wave_gemm<4, 1, LDX>(xS, wS, rowBase, colBase, acc, lane);
  __syncthreads();
  write_act_lds<0>(acc, b0, aS, rowBase, colBase, l15, lg);
  stage_w<128>(w1, 128, wS, LDP, 128, tid);
  __syncthreads();

  zero_acc<4>(acc);
  wave_gemm<4, 4, LDP>(aS, wS, rowBase, colBase, acc, lane);
  // h = tanh(. + b1); write h (bf16) and z0 (f32, = h so edge atomics produce h+agg)
  #pragma unroll
  for (int nf = 0; nf < 4; ++nf) {
    int col = colBase + 16 * nf + l15;
    float bv = b1[col];
    #pragma unroll
    for (int mf = 0; mf < 4; ++mf)
      #pragma unroll
      for (int i = 0; i < 4; ++i) {
        int row = rowBase + 16 * mf + 4 * lg + i;
        int node = nb + row;
        if (node < N) {
          float v = tanh_fast(acc[mf][nf][i] + bv);
          hB[node * 128 + col] = f2bf(v);
          z0[node * 128 + col] = v;
        }
      }
  }
}

// ---------------- Kernel 2: edge message + scatter-add.  z0[dst] += relu(h[src] + ew*elw + elb) ----------------
extern "C" __global__ void __launch_bounds__(256) edge_kernel(
    const int* __restrict__ ei, const float* __restrict__ ew,
    const float* __restrict__ elw, const float* __restrict__ elb,
    const unsigned short* __restrict__ hB, float* z0, int E) {
  const int lane = threadIdx.x & 63, wv = threadIdx.x >> 6;
  const float2 wl = *(const float2*)(elw + 2 * lane);
  const float2 bl = *(const float2*)(elb + 2 * lane);
  const int stride = gridDim.x * 4;
  for (int e = blockIdx.x * 4 + wv; e < E; e += stride) {
    int src = ei[e];
    int dst = ei[E + e];
    float w = ew[e];
    unsigned hv = *(const unsigned*)(hB + src * 128 + 2 * lane);
    float m0 = fmaxf(bflo(hv) + w * wl.x + bl.x, 0.0f);
    float m1 = fmaxf(bfhi(hv) + w * wl.y + bl.y, 0.0f);
    float* p = z0 + dst * 128 + 2 * lane;
    atomicAdd(p, m0);
    atomicAdd(p + 1, m1);
  }
}

// ---------------- Kernel 3: node MLP chain + post (skip-cat fused as two accumulating GEMMs) ----------------
extern "C" __global__ void __launch_bounds__(256, 2) node_kernel(
    const float* __restrict__ z0, const unsigned short* hB,
    const float* __restrict__ mw0, const float* __restrict__ mb0,
    const float* __restrict__ mw1, const float* __restrict__ mb1,
    const float* __restrict__ mw2, const float* __restrict__ mb2,
    const float* __restrict__ qw0, const float* __restrict__ qb0,
    const float* __restrict__ qw1, const float* __restrict__ qb1,
    float* out, int N) {
  __shared__ unsigned short aS[128 * LDP];
  __shared__ unsigned short wS[128 * LDP];
  const int tid = threadIdx.x, lane = tid & 63, wave = tid >> 6;
  const int l15 = lane & 15, lg = lane >> 4;
  const int wr = wave >> 1, wc = wave & 1;
  const int rowBase = 64 * wr, colBase = 64 * wc;
  const int nb = blockIdx.x * 128;

  // stage z0 tile -> bf16
  for (int i = tid; i < 128 * 32; i += 256) {
    int r = i >> 5, q = i & 31;
    int node = nb + r; node = node < N ? node : N - 1;
    float4 v = *(const float4*)(z0 + node * 128 + q * 4);
    ushort4 o; o.x = f2bf(v.x); o.y = f2bf(v.y); o.z = f2bf(v.z); o.w = f2bf(v.w);
    *(ushort4*)(aS + r * LDP + q * 4) = o;
  }
  stage_w<128>(mw0, 128, wS, LDP, 128, tid);
  __syncthreads();

  f32x4 acc[4][4];

  // mlp layer 0 (lrelu)
  zero_acc<4>(acc);
  wave_gemm<4, 4, LDP>(aS, wS, rowBase, colBase, acc, lane);
  __syncthreads();
  write_act_lds<0>(acc, mb0, aS, rowBase, colBase, l15, lg);
  stage_w<128>(mw1, 128, wS, LDP, 128, tid);
  __syncthreads();

  // mlp layer 1 (lrelu)
  zero_acc<4>(acc);
  wave_gemm<4, 4, LDP>(aS, wS, rowBase, colBase, acc, lane);
  __syncthreads();
  write_act_lds<0>(acc, mb1, aS, rowBase, colBase, l15, lg);
  stage_w<128>(mw2, 128, wS, LDP, 128, tid);
  __syncthreads();

  // mlp layer 2 (tanh) -> z3
  zero_acc<4>(acc);
  wave_gemm<4, 4, LDP>(aS, wS, rowBase, colBase, acc, lane);
  __syncthreads();
  write_act_lds<1>(acc, mb2, aS, rowBase, colBase, l15, lg);
  stage_w<128>(qw0, 256, wS, LDP, 128, tid);  // W0a = post_w0[:, :128]
  __syncthreads();

  // post layer 0: acc = W0a @ z3 ...
  zero_acc<4>(acc);
  wave_gemm<4, 4, LDP>(aS, wS, rowBase, colBase, acc, lane);
  __syncthreads();
  // ... then overwrite aS with the h tile (bf16 copy) and wS with W0b; acc += W0b @ h
  for (int i = tid; i < 128 * 16; i += 256) {
    int r = i >> 4, q = i & 15;
    int node = nb + r; node = node < N ? node : N - 1;
    uint4 v = *(const uint4*)(hB + node * 128 + q * 8);
    *(uint4*)(aS + r * LDP + q * 8) = v;
  }
  stage_w<128>(qw0 + 128, 256, wS, LDP, 128, tid);  // W0b = post_w0[:, 128:]
  __syncthreads();
  wave_gemm<4, 4, LDP>(aS, wS, rowBase, colBase, acc, lane);
  __syncthreads();
  write_act_lds<0>(acc, qb0, aS, rowBase, colBase, l15, lg);  // p
  stage_w<128>(qw1, 128, wS, LDP, 64, tid);
  __syncthreads();

  // post layer 1: [128] -> 64, tanh, direct global write
  f32x4 acc2[4][2];
  zero_acc<2>(acc2);
  wave_gemm<2, 4, LDP>(aS, wS, rowBase, 32 * wc, acc2, lane);
  #pragma unroll
  for (int nf = 0; nf < 2; ++nf) {
    int col = 32 * wc + 16 * nf + l15;
    float bv = qb1[col];
    #pragma unroll
    for (int mf = 0; mf < 4; ++mf)
      #pragma unroll
      for (int i = 0; i < 4; ++i) {
        int row = rowBase + 16 * mf + 4 * lg + i;
        int node = nb + row;
        if (node < N) out[node * 64 + col] = tanh_fast(acc2[mf][nf][i] + bv);
      }
  }
}

extern "C" void kernel_launch(void* const* d_in, const int* in_sizes, int n_in,
                              void* d_out, int out_size, void* d_ws, size_t ws_size,
                              hipStream_t stream) {
  const float* x   = (const float*)d_in[0];
  const int*   ei  = (const int*)d_in[1];
  const float* ew  = (const float*)d_in[2];
  const float* pw0 = (const float*)d_in[3];
  const float* pb0 = (const float*)d_in[4];
  const float* pw1 = (const float*)d_in[5];
  const float* pb1 = (const float*)d_in[6];
  const float* elw = (const float*)d_in[7];
  const float* elb = (const float*)d_in[8];
  const float* mw0 = (const float*)d_in[9];
  const float* mb0 = (const float*)d_in[10];
  const float* mw1 = (const float*)d_in[11];
  const float* mb1 = (const float*)d_in[12];
  const float* mw2 = (const float*)d_in[13];
  const float* mb2 = (const float*)d_in[14];
  const float* qw0 = (const float*)d_in[15];
  const float* qb0 = (const float*)d_in[16];
  const float* qw1 = (const float*)d_in[17];
  const float* qb1 = (const float*)d_in[18];
  float* out = (float*)d_out;

  const int N = in_sizes[0] / 16;
  const int E = in_sizes[1] / 2;

  float* z0 = (float*)d_ws;                               // N*128 f32 (atomic target, init = h)
  size_t z0_bytes = (size_t)N * 128 * sizeof(float);
  size_t hB_bytes = (size_t)N * 128 * sizeof(unsigned short);
  unsigned short* hB;
  if (ws_size >= z0_bytes + hB_bytes) {
    hB = (unsigned short*)((char*)d_ws + z0_bytes);
  } else {
    // exact byte fit: N*64 f32 out == N*128 bf16; per-node ranges are read (post0) before written (post1)
    hB = (unsigned short*)d_out;
  }

  const int nblk = (N + 127) / 128;
  prep_kernel<<<dim3(nblk), dim3(256), 0, stream>>>(x, pw0, pb0, pw1, pb1, hB, z0, N);
  edge_kernel<<<dim3(4096), dim3(256), 0, stream>>>(ei, ew, elw, elb, hB, z0, E);
  node_kernel<<<dim3(nblk), dim3(256), 0, stream>>>(z0, hB, mw0, mb0, mw1, mb1, mw2, mb2,
                                                    qw0, qb0, qw1, qb1, out, N);
}

// Round 2
// 309.618 us; speedup vs baseline: 1.7777x; 1.7777x over previous
//
#include <hip/hip_runtime.h>

typedef short bf16x8 __attribute__((ext_vector_type(8)));
typedef float f32x4 __attribute__((ext_vector_type(4)));

#define LDP 136   // padded stride (bf16 elems) for 128-wide LDS tiles: 272B rows -> 2-way bank alias (free)
#define LDX 40    // padded stride for the 32-wide x tile
#define NEG 0.01f

__device__ __forceinline__ unsigned short f2bf(float f) {
  union { float f; unsigned u; } v; v.f = f;
  unsigned u = v.u;
  return (unsigned short)((u + 0x7fffu + ((u >> 16) & 1u)) >> 16);
}
__device__ __forceinline__ float bflo(unsigned u) { return __uint_as_float(u << 16); }
__device__ __forceinline__ float bfhi(unsigned u) { return __uint_as_float(u & 0xffff0000u); }

__device__ __forceinline__ float lrelu(float v) {
  return fmaxf(v, 0.0f) + NEG * fminf(v, 0.0f);
}
__device__ __forceinline__ float tanh_fast(float x) {
  float e = __expf(2.0f * x);
  return 1.0f - __fdividef(2.0f, e + 1.0f);
}

// Stage a [rows x COLS] f32 weight (row stride gld) -> bf16 LDS tile (row stride lds)
template<int COLS>
__device__ __forceinline__ void stage_w(const float* __restrict__ g, int gld,
                                        unsigned short* s, int lds, int rows, int tid) {
  const int perRow = COLS / 4;
  const int total = rows * perRow;
  for (int i = tid; i < total; i += 256) {
    int r = i / perRow, q = i - r * perRow;
    float4 v = *(const float4*)(g + r * gld + q * 4);
    ushort4 o; o.x = f2bf(v.x); o.y = f2bf(v.y); o.z = f2bf(v.z); o.w = f2bf(v.w);
    *(ushort4*)(s + r * lds + q * 4) = o;
  }
}

// Copy a [rows x 128] bf16 slab (contiguous) into LDS tile (stride LDP), 16B chunks
__device__ __forceinline__ void stage_bf(const unsigned short* __restrict__ g,
                                         unsigned short* s, int rows, int tid) {
  const int total = rows * 16;
  for (int i = tid; i < total; i += 256) {
    int r = i >> 4, q = i & 15;
    *(uint4*)(s + r * LDP + q * 8) = *(const uint4*)(g + r * 128 + q * 8);
  }
}

template<int NF>
__device__ __forceinline__ void zero_acc(f32x4 acc[4][NF]) {
  #pragma unroll
  for (int m = 0; m < 4; ++m)
    #pragma unroll
    for (int n = 0; n < NF; ++n) {
      f32x4 z = {0.f, 0.f, 0.f, 0.f};
      acc[m][n] = z;
    }
}

// Wave GEMM: out rows [rowBase,+64) x cols [colBase,+16*NF).  A row=node,col=k; B row=out_ch,col=k.
template<int NF, int KSTEPS, int LDA>
__device__ __forceinline__ void wave_gemm(const unsigned short* aS, const unsigned short* wS,
                                          int rowBase, int colBase, f32x4 acc[4][NF], int lane) {
  const int l15 = lane & 15, lg = lane >> 4;
  #pragma unroll
  for (int ks = 0; ks < KSTEPS; ++ks) {
    const int k = ks * 32 + lg * 8;
    bf16x8 a[4], b[NF];
    #pragma unroll
    for (int mf = 0; mf < 4; ++mf)
      a[mf] = *(const bf16x8*)(aS + (rowBase + 16 * mf + l15) * LDA + k);
    #pragma unroll
    for (int nf = 0; nf < NF; ++nf)
      b[nf] = *(const bf16x8*)(wS + (colBase + 16 * nf + l15) * LDP + k);
    #pragma unroll
    for (int mf = 0; mf < 4; ++mf)
      #pragma unroll
      for (int nf = 0; nf < NF; ++nf)
        acc[mf][nf] = __builtin_amdgcn_mfma_f32_16x16x32_bf16(a[mf], b[nf], acc[mf][nf], 0, 0, 0);
  }
}

template<int ACT>  // 0 = lrelu, 1 = tanh
__device__ __forceinline__ void write_act_lds(f32x4 acc[4][4], const float* __restrict__ bias,
                                              unsigned short* aS, int rowBase, int colBase,
                                              int l15, int lg) {
  #pragma unroll
  for (int nf = 0; nf < 4; ++nf) {
    int col = colBase + 16 * nf + l15;
    float bv = bias[col];
    #pragma unroll
    for (int mf = 0; mf < 4; ++mf)
      #pragma unroll
      for (int i = 0; i < 4; ++i) {
        int row = rowBase + 16 * mf + 4 * lg + i;
        float v = acc[mf][nf][i] + bv;
        v = (ACT == 0) ? lrelu(v) : tanh_fast(v);
        aS[row * LDP + col] = f2bf(v);
      }
  }
}

// ---------------- weight convert (f32 -> bf16 slabs) + deg zero ----------------
// wbf layout (bf16 elems): mw0@0, mw1@16384, mw2@32768, qw0a@49152, qw0b@65536, qw1@81920 (64x128)
extern "C" __global__ void __launch_bounds__(256) wconv_kernel(
    const float* __restrict__ mw0, const float* __restrict__ mw1, const float* __restrict__ mw2,
    const float* __restrict__ qw0, const float* __restrict__ qw1,
    unsigned short* wbf, int* deg, int N) {
  int gid = blockIdx.x * 256 + threadIdx.x;
  if (gid < 22528) {
    int f = gid;
    float4 v;
    if (f < 12288) {
      const float* m = (f < 4096) ? mw0 : ((f < 8192) ? mw1 : mw2);
      v = *(const float4*)(m + (size_t)(f & 4095) * 4);
    } else if (f < 20480) {
      int g = f - 12288; int half = g >> 12; int r = (g & 4095) >> 5, q = g & 31;
      v = *(const float4*)(qw0 + r * 256 + half * 128 + q * 4);
    } else {
      int g = f - 20480;
      v = *(const float4*)(qw1 + g * 4);
    }
    ushort4 o; o.x = f2bf(v.x); o.y = f2bf(v.y); o.z = f2bf(v.z); o.w = f2bf(v.w);
    *(ushort4*)(wbf + gid * 4) = o;
  }
  if (gid < N) deg[gid] = 0;
}

// ---------------- Kernel 1: prep MLP.  x[N,16] -> h (bf16) ----------------
extern "C" __global__ void __launch_bounds__(256, 2) prep_kernel(
    const float* __restrict__ x,
    const float* __restrict__ w0, const float* __restrict__ b0,
    const float* __restrict__ w1, const float* __restrict__ b1,
    unsigned short* hB, int N) {
  __shared__ unsigned short xS[128 * LDX];
  __shared__ unsigned short aS[128 * LDP];
  __shared__ unsigned short wS[128 * LDP];
  const int tid = threadIdx.x, lane = tid & 63, wave = tid >> 6;
  const int l15 = lane & 15, lg = lane >> 4;
  const int wr = wave >> 1, wc = wave & 1;
  const int rowBase = 64 * wr, colBase = 64 * wc;
  const int nb = blockIdx.x * 128;

  for (int i = tid; i < 128 * 4; i += 256) {
    int r = i >> 2, q = i & 3;
    int node = nb + r; node = node < N ? node : N - 1;
    float4 v = *(const float4*)(x + node * 16 + q * 4);
    ushort4 o; o.x = f2bf(v.x); o.y = f2bf(v.y); o.z = f2bf(v.z); o.w = f2bf(v.w);
    *(ushort4*)(xS + r * LDX + q * 4) = o;
    ushort4 zz; zz.x = 0; zz.y = 0; zz.z = 0; zz.w = 0;
    *(ushort4*)(xS + r * LDX + 16 + q * 4) = zz;
  }
  stage_w<16>(w0, 16, wS, LDP, 128, tid);
  for (int i = tid; i < 128 * 4; i += 256) {
    int r = i >> 2, q = i & 3;
    ushort4 zz; zz.x = 0; zz.y = 0; zz.z = 0; zz.w = 0;
    *(ushort4*)(wS + r * LDP + 16 + q * 4) = zz;
  }
  __syncthreads();

  f32x4 acc[4][4];
  zero_acc<4>(acc);
  wave_gemm<4, 1, LDX>(xS, wS, rowBase, colBase, acc, lane);
  __syncthreads();
  write_act_lds<0>(acc, b0, aS, rowBase, colBase, l15, lg);
  stage_w<128>(w1, 128, wS, LDP, 128, tid);
  __syncthreads();

  zero_acc<4>(acc);
  wave_gemm<4, 4, LDP>(aS, wS, rowBase, colBase, acc, lane);
  #pragma unroll
  for (int nf = 0; nf < 4; ++nf) {
    int col = colBase + 16 * nf + l15;
    float bv = b1[col];
    #pragma unroll
    for (int mf = 0; mf < 4; ++mf)
      #pragma unroll
      for (int i = 0; i < 4; ++i) {
        int row = rowBase + 16 * mf + 4 * lg + i;
        int node = nb + row;
        if (node < N) hB[node * 128 + col] = f2bf(tanh_fast(acc[mf][nf][i] + bv));
      }
  }
}

// ---------------- CSR build ----------------
extern "C" __global__ void __launch_bounds__(256) hist_kernel(const int* __restrict__ ei,
                                                              int* deg, int E) {
  int e = blockIdx.x * 256 + threadIdx.x;
  if (e < E) atomicAdd(&deg[ei[E + e]], 1);
}

extern "C" __global__ void __launch_bounds__(256) scan_partials_kernel(
    const int* __restrict__ deg, int* partials, int N) {
  __shared__ int red[256];
  int b = blockIdx.x, t = threadIdx.x;
  int base = b * 2048 + t * 8, s = 0;
  #pragma unroll
  for (int i = 0; i < 8; ++i) { int idx = base + i; s += (idx < N) ? deg[idx] : 0; }
  red[t] = s; __syncthreads();
  for (int off = 128; off > 0; off >>= 1) {
    if (t < off) red[t] += red[t + off];
    __syncthreads();
  }
  if (t == 0) partials[b] = red[0];
}

extern "C" __global__ void scan_base_kernel(const int* __restrict__ partials, int* basearr, int nb) {
  int lane = threadIdx.x;
  int orig = (lane < nb) ? partials[lane] : 0;
  int v = orig;
  #pragma unroll
  for (int off = 1; off < 64; off <<= 1) {
    int u = __shfl_up(v, off);
    if (lane >= off) v += u;
  }
  if (lane < nb) basearr[lane] = v - orig;  // exclusive
}

extern "C" __global__ void __launch_bounds__(256) scan_apply_kernel(
    const int* __restrict__ deg, const int* __restrict__ basearr,
    int* offs, int* cur, int N) {
  __shared__ int sc[256];
  int b = blockIdx.x, t = threadIdx.x;
  int base = b * 2048 + t * 8;
  int loc[8], s = 0;
  #pragma unroll
  for (int i = 0; i < 8; ++i) { int idx = base + i; loc[i] = (idx < N) ? deg[idx] : 0; s += loc[i]; }
  sc[t] = s; __syncthreads();
  for (int off = 1; off < 256; off <<= 1) {
    int v = sc[t];
    int u = (t >= off) ? sc[t - off] : 0;
    __syncthreads();
    sc[t] = v + u;
    __syncthreads();
  }
  int run = basearr[b] + ((t == 0) ? 0 : sc[t - 1]);
  #pragma unroll
  for (int i = 0; i < 8; ++i) {
    int idx = base + i;
    if (idx < N) { offs[idx] = run; cur[idx] = run; run += loc[i]; }
  }
}

extern "C" __global__ void __launch_bounds__(256) scatter_kernel(
    const int* __restrict__ ei, const float* __restrict__ ew,
    int* cur, int2* recs, int E) {
  int e = blockIdx.x * 256 + threadIdx.x;
  if (e < E) {
    int dst = ei[E + e];
    int slot = atomicAdd(&cur[dst], 1);
    int2 r; r.x = ei[e]; r.y = __float_as_int(ew[e]);
    recs[slot] = r;
  }
}

// ---------------- aggregation: z = h_dst + sum_j relu(h_src + w*elw + elb), bf16 out ----------------
extern "C" __global__ void __launch_bounds__(256) agg_kernel(
    const int* __restrict__ offs, const int* __restrict__ cur,
    const int2* __restrict__ recs,
    const float* __restrict__ elw, const float* __restrict__ elb,
    const unsigned short* __restrict__ hB, unsigned short* zB, int N) {
  const int lane = threadIdx.x & 63, wv = threadIdx.x >> 6;
  const int node = blockIdx.x * 4 + wv;
  if (node >= N) return;
  const float2 wl = *(const float2*)(elw + 2 * lane);
  const float2 bl = *(const float2*)(elb + 2 * lane);
  const int s = offs[node], epos = cur[node];  // cur == end after scatter
  float c0 = 0.f, c1 = 0.f;
  for (int j = s; j < epos; ++j) {
    int2 rec = recs[j];
    float w = __int_as_float(rec.y);
    unsigned hv = *(const unsigned*)(hB + (size_t)rec.x * 128 + 2 * lane);
    c0 += fmaxf(bflo(hv) + w * wl.x + bl.x, 0.0f);
    c1 += fmaxf(bfhi(hv) + w * wl.y + bl.y, 0.0f);
  }
  unsigned hself = *(const unsigned*)(hB + (size_t)node * 128 + 2 * lane);
  float z0v = bflo(hself) + c0, z1v = bfhi(hself) + c1;
  unsigned o = ((unsigned)f2bf(z1v) << 16) | (unsigned)f2bf(z0v);
  *(unsigned*)(zB + (size_t)node * 128 + 2 * lane) = o;
}

// ---------------- node MLP chain + post ----------------
extern "C" __global__ void __launch_bounds__(256, 2) node_kernel(
    const unsigned short* __restrict__ zB, const unsigned short* __restrict__ hB,
    const unsigned short* __restrict__ wbf,
    const float* __restrict__ mb0, const float* __restrict__ mb1, const float* __restrict__ mb2,
    const float* __restrict__ qb0, const float* __restrict__ qb1,
    float* out, int N) {
  __shared__ unsigned short aS[128 * LDP];
  __shared__ unsigned short wS[128 * LDP];
  const int tid = threadIdx.x, lane = tid & 63, wave = tid >> 6;
  const int l15 = lane & 15, lg = lane >> 4;
  const int wr = wave >> 1, wc = wave & 1;
  const int rowBase = 64 * wr, colBase = 64 * wc;
  const int nb = blockIdx.x * 128;

  // stage z tile (bf16 copy; clamp OOB rows to node N-1)
  for (int i = tid; i < 128 * 16; i += 256) {
    int r = i >> 4, q = i & 15;
    int node = nb + r; node = node < N ? node : N - 1;
    *(uint4*)(aS + r * LDP + q * 8) = *(const uint4*)(zB + (size_t)node * 128 + q * 8);
  }
  stage_bf(wbf, wS, 128, tid);            // mw0
  __syncthreads();

  f32x4 acc[4][4];

  zero_acc<4>(acc);
  wave_gemm<4, 4, LDP>(aS, wS, rowBase, colBase, acc, lane);
  __syncthreads();
  write_act_lds<0>(acc, mb0, aS, rowBase, colBase, l15, lg);
  stage_bf(wbf + 16384, wS, 128, tid);    // mw1
  __syncthreads();

  zero_acc<4>(acc);
  wave_gemm<4, 4, LDP>(aS, wS, rowBase, colBase, acc, lane);
  __syncthreads();
  write_act_lds<0>(acc, mb1, aS, rowBase, colBase, l15, lg);
  stage_bf(wbf + 32768, wS, 128, tid);    // mw2
  __syncthreads();

  zero_acc<4>(acc);
  wave_gemm<4, 4, LDP>(aS, wS, rowBase, colBase, acc, lane);
  __syncthreads();
  write_act_lds<1>(acc, mb2, aS, rowBase, colBase, l15, lg);
  stage_bf(wbf + 49152, wS, 128, tid);    // qw0a
  __syncthreads();

  zero_acc<4>(acc);
  wave_gemm<4, 4, LDP>(aS, wS, rowBase, colBase, acc, lane);
  __syncthreads();
  for (int i = tid; i < 128 * 16; i += 256) {
    int r = i >> 4, q = i & 15;
    int node = nb + r; node = node < N ? node : N - 1;
    *(uint4*)(aS + r * LDP + q * 8) = *(const uint4*)(hB + (size_t)node * 128 + q * 8);
  }
  stage_bf(wbf + 65536, wS, 128, tid);    // qw0b
  __syncthreads();
  wave_gemm<4, 4, LDP>(aS, wS, rowBase, colBase, acc, lane);
  __syncthreads();
  write_act_lds<0>(acc, qb0, aS, rowBase, colBase, l15, lg);
  stage_bf(wbf + 81920, wS, 64, tid);     // qw1
  __syncthreads();

  f32x4 acc2[4][2];
  zero_acc<2>(acc2);
  wave_gemm<2, 4, LDP>(aS, wS, rowBase, 32 * wc, acc2, lane);
  #pragma unroll
  for (int nf = 0; nf < 2; ++nf) {
    int col = 32 * wc + 16 * nf + l15;
    float bv = qb1[col];
    #pragma unroll
    for (int mf = 0; mf < 4; ++mf)
      #pragma unroll
      for (int i = 0; i < 4; ++i) {
        int row = rowBase + 16 * mf + 4 * lg + i;
        int node = nb + row;
        if (node < N) out[(size_t)node * 64 + col] = tanh_fast(acc2[mf][nf][i] + bv);
      }
  }
}

extern "C" void kernel_launch(void* const* d_in, const int* in_sizes, int n_in,
                              void* d_out, int out_size, void* d_ws, size_t ws_size,
                              hipStream_t stream) {
  const float* x   = (const float*)d_in[0];
  const int*   ei  = (const int*)d_in[1];
  const float* ew  = (const float*)d_in[2];
  const float* pw0 = (const float*)d_in[3];
  const float* pb0 = (const float*)d_in[4];
  const float* pw1 = (const float*)d_in[5];
  const float* pb1 = (const float*)d_in[6];
  const float* elw = (const float*)d_in[7];
  const float* elb = (const float*)d_in[8];
  const float* mw0 = (const float*)d_in[9];
  const float* mb0 = (const float*)d_in[10];
  const float* mw1 = (const float*)d_in[11];
  const float* mb1 = (const float*)d_in[12];
  const float* mw2 = (const float*)d_in[13];
  const float* mb2 = (const float*)d_in[14];
  const float* qw0 = (const float*)d_in[15];
  const float* qb0 = (const float*)d_in[16];
  const float* qw1 = (const float*)d_in[17];
  const float* qb1 = (const float*)d_in[18];
  float* out = (float*)d_out;

  const int N = in_sizes[0] / 16;
  const int E = in_sizes[1] / 2;

  // workspace carve-up (256B aligned)
  char* p = (char*)d_ws;
  auto alloc = [&](size_t bytes) { char* r = p; p += (bytes + 255) & ~(size_t)255; return r; };
  const size_t hB_bytes = (size_t)N * 128 * 2;

  unsigned short* zB   = (unsigned short*)alloc(hB_bytes);
  int2*           recs = (int2*)alloc((size_t)E * 8);
  int*            deg  = (int*)alloc((size_t)N * 4);
  int*            offs = (int*)alloc((size_t)N * 4);
  int*            cur  = (int*)alloc((size_t)N * 4);
  int*            part = (int*)alloc(256 * 4);
  int*            basearr = (int*)alloc(256 * 4);
  unsigned short* wbf  = (unsigned short*)alloc(90112 * 2);

  unsigned short* hB;
  if ((size_t)(p - (char*)d_ws) + hB_bytes <= ws_size) {
    hB = (unsigned short*)alloc(hB_bytes);
  } else {
    // alias output: N*64 f32 == N*128 bf16; node_kernel reads own h rows before writing own out rows
    hB = (unsigned short*)d_out;
  }

  const int nblk  = (N + 127) / 128;
  const int nb1   = (N + 2047) / 2048;   // scan blocks (<=64 for N<=131072)
  const int eblk  = (E + 255) / 256;
  const int wconv_threads = (N > 22528) ? N : 22528;

  wconv_kernel<<<dim3((wconv_threads + 255) / 256), dim3(256), 0, stream>>>(
      mw0, mw1, mw2, qw0, qw1, wbf, deg, N);
  prep_kernel<<<dim3(nblk), dim3(256), 0, stream>>>(x, pw0, pb0, pw1, pb1, hB, N);
  hist_kernel<<<dim3(eblk), dim3(256), 0, stream>>>(ei, deg, E);
  scan_partials_kernel<<<dim3(nb1), dim3(256), 0, stream>>>(deg, part, N);
  scan_base_kernel<<<dim3(1), dim3(64), 0, stream>>>(part, basearr, nb1);
  scan_apply_kernel<<<dim3(nb1), dim3(256), 0, stream>>>(deg, basearr, offs, cur, N);
  scatter_kernel<<<dim3(eblk), dim3(256), 0, stream>>>(ei, ew, cur, recs, E);
  agg_kernel<<<dim3((N + 3) / 4), dim3(256), 0, stream>>>(offs, cur, recs, elw, elb, hB, zB, N);
  node_kernel<<<dim3(nblk), dim3(256), 0, stream>>>(zB, hB, wbf, mb0, mb1, mb2, qb0, qb1, out, N);
}

// Round 3
// 287.393 us; speedup vs baseline: 1.9152x; 1.0773x over previous
//
#include <hip/hip_runtime.h>

typedef short bf16x8 __attribute__((ext_vector_type(8)));
typedef float f32x4 __attribute__((ext_vector_type(4)));

#define LDP 136   // padded stride (bf16 elems) for 128-wide LDS tiles
#define LDX 40    // padded stride for the 32-wide x tile
#define NEG 0.01f

__device__ __forceinline__ unsigned short f2bf(float f) {
  union { float f; unsigned u; } v; v.f = f;
  unsigned u = v.u;
  return (unsigned short)((u + 0x7fffu + ((u >> 16) & 1u)) >> 16);
}
__device__ __forceinline__ unsigned pack2(float a, float b) {
  return ((unsigned)f2bf(b) << 16) | (unsigned)f2bf(a);
}
__device__ __forceinline__ float bflo(unsigned u) { return __uint_as_float(u << 16); }
__device__ __forceinline__ float bfhi(unsigned u) { return __uint_as_float(u & 0xffff0000u); }

__device__ __forceinline__ float lrelu(float v) {
  return fmaxf(v, 0.0f) + NEG * fminf(v, 0.0f);
}
__device__ __forceinline__ float tanh_fast(float x) {
  float e = __expf(2.0f * x);
  return 1.0f - __fdividef(2.0f, e + 1.0f);
}

// Stage a [rows x COLS] f32 weight (row stride gld) -> bf16 LDS tile (row stride lds)
template<int COLS>
__device__ __forceinline__ void stage_w(const float* __restrict__ g, int gld,
                                        unsigned short* s, int lds, int rows, int tid) {
  const int perRow = COLS / 4;
  const int total = rows * perRow;
  for (int i = tid; i < total; i += 256) {
    int r = i / perRow, q = i - r * perRow;
    float4 v = *(const float4*)(g + r * gld + q * 4);
    ushort4 o; o.x = f2bf(v.x); o.y = f2bf(v.y); o.z = f2bf(v.z); o.w = f2bf(v.w);
    *(ushort4*)(s + r * lds + q * 4) = o;
  }
}

// Copy a [rows x 128] bf16 slab (contiguous) into LDS tile (stride LDP), 16B chunks
__device__ __forceinline__ void stage_bf(const unsigned short* __restrict__ g,
                                         unsigned short* s, int rows, int tid) {
  const int total = rows * 16;
  for (int i = tid; i < total; i += 256) {
    int r = i >> 4, q = i & 15;
    *(uint4*)(s + r * LDP + q * 8) = *(const uint4*)(g + r * 128 + q * 8);
  }
}

template<int MF, int NF>
__device__ __forceinline__ void zero_acc(f32x4 acc[MF][NF]) {
  #pragma unroll
  for (int m = 0; m < MF; ++m)
    #pragma unroll
    for (int n = 0; n < NF; ++n) {
      f32x4 z = {0.f, 0.f, 0.f, 0.f};
      acc[m][n] = z;
    }
}

// Wave GEMM, transposed orientation: D[ch][node].
// A = weights from wS: rows chBase+16mf+l15 (out_ch), k contiguous.
// B = acts from bS:    rows nodeBase+16nf+l15 (node), k contiguous.
// D: col = node = lane&15, row = out_ch = 4*(lane>>4)+reg.
template<int MF, int NF, int KSTEPS, int LDB>
__device__ __forceinline__ void wave_gemm(const unsigned short* wS, const unsigned short* bS,
                                          int chBase, int nodeBase, f32x4 acc[MF][NF], int lane) {
  const int l15 = lane & 15, lg = lane >> 4;
  #pragma unroll
  for (int ks = 0; ks < KSTEPS; ++ks) {
    const int k = ks * 32 + lg * 8;
    bf16x8 a[MF], b[NF];
    #pragma unroll
    for (int mf = 0; mf < MF; ++mf)
      a[mf] = *(const bf16x8*)(wS + (chBase + 16 * mf + l15) * LDP + k);
    #pragma unroll
    for (int nf = 0; nf < NF; ++nf)
      b[nf] = *(const bf16x8*)(bS + (nodeBase + 16 * nf + l15) * LDB + k);
    #pragma unroll
    for (int mf = 0; mf < MF; ++mf)
      #pragma unroll
      for (int nf = 0; nf < NF; ++nf)
        acc[mf][nf] = __builtin_amdgcn_mfma_f32_16x16x32_bf16(a[mf], b[nf], acc[mf][nf], 0, 0, 0);
  }
}

// Epilogue: lane holds 4 consecutive out-channels (ch4..ch4+3) for node = nodeBase+16nf+l15.
// One b64 LDS write per fragment.
template<int ACT>  // 0 = lrelu, 1 = tanh
__device__ __forceinline__ void write_act_lds_T(f32x4 acc[4][4], const float* __restrict__ bias,
                                                unsigned short* aS, int chBase, int nodeBase,
                                                int l15, int lg) {
  #pragma unroll
  for (int mf = 0; mf < 4; ++mf) {
    const int ch4 = chBase + 16 * mf + 4 * lg;
    const float4 bv = *(const float4*)(bias + ch4);
    #pragma unroll
    for (int nf = 0; nf < 4; ++nf) {
      const int node = nodeBase + 16 * nf + l15;
      float v0 = acc[mf][nf][0] + bv.x;
      float v1 = acc[mf][nf][1] + bv.y;
      float v2 = acc[mf][nf][2] + bv.z;
      float v3 = acc[mf][nf][3] + bv.w;
      if (ACT == 0) { v0 = lrelu(v0); v1 = lrelu(v1); v2 = lrelu(v2); v3 = lrelu(v3); }
      else { v0 = tanh_fast(v0); v1 = tanh_fast(v1); v2 = tanh_fast(v2); v3 = tanh_fast(v3); }
      uint2 o; o.x = pack2(v0, v1); o.y = pack2(v2, v3);
      *(uint2*)(aS + node * LDP + ch4) = o;
    }
  }
}

// ---------------- weight convert (f32 -> bf16 slabs) + deg zero ----------------
// wbf layout (bf16 elems): mw0@0, mw1@16384, mw2@32768, qw0a@49152, qw0b@65536, qw1@81920 (64x128)
extern "C" __global__ void __launch_bounds__(256) wconv_kernel(
    const float* __restrict__ mw0, const float* __restrict__ mw1, const float* __restrict__ mw2,
    const float* __restrict__ qw0, const float* __restrict__ qw1,
    unsigned short* wbf, int* deg, int N) {
  int gid = blockIdx.x * 256 + threadIdx.x;
  if (gid < 22528) {
    int f = gid;
    float4 v;
    if (f < 12288) {
      const float* m = (f < 4096) ? mw0 : ((f < 8192) ? mw1 : mw2);
      v = *(const float4*)(m + (size_t)(f & 4095) * 4);
    } else if (f < 20480) {
      int g = f - 12288; int half = g >> 12; int r = (g & 4095) >> 5, q = g & 31;
      v = *(const float4*)(qw0 + r * 256 + half * 128 + q * 4);
    } else {
      int g = f - 20480;
      v = *(const float4*)(qw1 + g * 4);
    }
    ushort4 o; o.x = f2bf(v.x); o.y = f2bf(v.y); o.z = f2bf(v.z); o.w = f2bf(v.w);
    *(ushort4*)(wbf + gid * 4) = o;
  }
  if (gid < N) deg[gid] = 0;
}

// ---------------- Kernel 1: prep MLP (+ fused dst-degree histogram) ----------------
extern "C" __global__ void __launch_bounds__(256, 2) prep_kernel(
    const float* __restrict__ x,
    const float* __restrict__ w0, const float* __restrict__ b0,
    const float* __restrict__ w1, const float* __restrict__ b1,
    const int* __restrict__ ei, int* deg, int E,
    unsigned short* hB, int N) {
  __shared__ unsigned short xS[128 * LDX];
  __shared__ unsigned short aS[128 * LDP];
  __shared__ unsigned short wS[128 * LDP];
  const int tid = threadIdx.x, lane = tid & 63, wave = tid >> 6;
  const int l15 = lane & 15, lg = lane >> 4;
  const int wr = wave >> 1, wc = wave & 1;
  const int chBase = 64 * wr, nodeBase = 64 * wc;
  const int nb = blockIdx.x * 128;

  // stage x tile (zero-padded k=16..31), w0 (zero-padded), fused histogram
  for (int i = tid; i < 128 * 4; i += 256) {
    int r = i >> 2, q = i & 3;
    int node = nb + r; node = node < N ? node : N - 1;
    float4 v = *(const float4*)(x + node * 16 + q * 4);
    ushort4 o; o.x = f2bf(v.x); o.y = f2bf(v.y); o.z = f2bf(v.z); o.w = f2bf(v.w);
    *(ushort4*)(xS + r * LDX + q * 4) = o;
    ushort4 zz; zz.x = 0; zz.y = 0; zz.z = 0; zz.w = 0;
    *(ushort4*)(xS + r * LDX + 16 + q * 4) = zz;
  }
  stage_w<16>(w0, 16, wS, LDP, 128, tid);
  for (int i = tid; i < 128 * 4; i += 256) {
    int r = i >> 2, q = i & 3;
    ushort4 zz; zz.x = 0; zz.y = 0; zz.z = 0; zz.w = 0;
    *(ushort4*)(wS + r * LDP + 16 + q * 4) = zz;
  }
  // fused histogram of dst (deg zeroed by wconv_kernel, which runs before)
  for (int e = blockIdx.x * 256 + tid; e < E; e += gridDim.x * 256)
    atomicAdd(&deg[ei[E + e]], 1);
  __syncthreads();

  f32x4 acc[4][4];
  zero_acc<4, 4>(acc);
  wave_gemm<4, 4, 1, LDX>(wS, xS, chBase, nodeBase, acc, lane);
  __syncthreads();
  write_act_lds_T<0>(acc, b0, aS, chBase, nodeBase, l15, lg);
  stage_w<128>(w1, 128, wS, LDP, 128, tid);
  __syncthreads();

  zero_acc<4, 4>(acc);
  wave_gemm<4, 4, 4, LDP>(wS, aS, chBase, nodeBase, acc, lane);
  // h = tanh(. + b1) -> packed 8B global stores
  #pragma unroll
  for (int mf = 0; mf < 4; ++mf) {
    const int ch4 = chBase + 16 * mf + 4 * lg;
    const float4 bv = *(const float4*)(b1 + ch4);
    #pragma unroll
    for (int nf = 0; nf < 4; ++nf) {
      const int node = nb + nodeBase + 16 * nf + l15;
      if (node < N) {
        float v0 = tanh_fast(acc[mf][nf][0] + bv.x);
        float v1 = tanh_fast(acc[mf][nf][1] + bv.y);
        float v2 = tanh_fast(acc[mf][nf][2] + bv.z);
        float v3 = tanh_fast(acc[mf][nf][3] + bv.w);
        uint2 o; o.x = pack2(v0, v1); o.y = pack2(v2, v3);
        *(uint2*)(hB + (size_t)node * 128 + ch4) = o;
      }
    }
  }
}

// ---------------- CSR scan (N <= 131072: nb1 <= 64) ----------------
extern "C" __global__ void __launch_bounds__(256) scan_partials_kernel(
    const int* __restrict__ deg, int* partials, int N) {
  __shared__ int red[256];
  int b = blockIdx.x, t = threadIdx.x;
  int base = b * 2048 + t * 8, s = 0;
  #pragma unroll
  for (int i = 0; i < 8; ++i) { int idx = base + i; s += (idx < N) ? deg[idx] : 0; }
  red[t] = s; __syncthreads();
  for (int off = 128; off > 0; off >>= 1) {
    if (t < off) red[t] += red[t + off];
    __syncthreads();
  }
  if (t == 0) partials[b] = red[0];
}

extern "C" __global__ void scan_base_kernel(const int* __restrict__ partials, int* basearr, int nb) {
  int lane = threadIdx.x;
  int orig = (lane < nb) ? partials[lane] : 0;
  int v = orig;
  #pragma unroll
  for (int off = 1; off < 64; off <<= 1) {
    int u = __shfl_up(v, off);
    if (lane >= off) v += u;
  }
  if (lane < nb) basearr[lane] = v - orig;  // exclusive
}

extern "C" __global__ void __launch_bounds__(256) scan_apply_kernel(
    const int* __restrict__ deg, const int* __restrict__ basearr,
    int* offs, int* cur, int N) {
  __shared__ int sc[256];
  int b = blockIdx.x, t = threadIdx.x;
  int base = b * 2048 + t * 8;
  int loc[8], s = 0;
  #pragma unroll
  for (int i = 0; i < 8; ++i) { int idx = base + i; loc[i] = (idx < N) ? deg[idx] : 0; s += loc[i]; }
  sc[t] = s; __syncthreads();
  for (int off = 1; off < 256; off <<= 1) {
    int v = sc[t];
    int u = (t >= off) ? sc[t - off] : 0;
    __syncthreads();
    sc[t] = v + u;
    __syncthreads();
  }
  int run = basearr[b] + ((t == 0) ? 0 : sc[t - 1]);
  #pragma unroll
  for (int i = 0; i < 8; ++i) {
    int idx = base + i;
    if (idx < N) { offs[idx] = run; cur[idx] = run; run += loc[i]; }
  }
}

extern "C" __global__ void __launch_bounds__(256) scatter_kernel(
    const int* __restrict__ ei, const float* __restrict__ ew,
    int* cur, int2* recs, int E) {
  int e = blockIdx.x * 256 + threadIdx.x;
  if (e < E) {
    int dst = ei[E + e];
    int slot = atomicAdd(&cur[dst], 1);
    int2 r; r.x = ei[e]; r.y = __float_as_int(ew[e]);
    recs[slot] = r;
  }
}

// ---------------- aggregation: z = h_dst + sum_j relu(h_src + w*elw + elb), bf16 out ----------------
extern "C" __global__ void __launch_bounds__(256) agg_kernel(
    const int* __restrict__ offs, const int* __restrict__ cur,
    const int2* __restrict__ recs,
    const float* __restrict__ elw, const float* __restrict__ elb,
    const unsigned short* __restrict__ hB, unsigned short* zB, int N) {
  const int lane = threadIdx.x & 63, wv = threadIdx.x >> 6;
  const int node = blockIdx.x * 4 + wv;
  if (node >= N) return;
  const float2 wl = *(const float2*)(elw + 2 * lane);
  const float2 bl = *(const float2*)(elb + 2 * lane);
  const int s = offs[node], epos = cur[node];  // cur == end after scatter
  float c0 = 0.f, c1 = 0.f;
  for (int j = s; j < epos; ++j) {
    int2 rec = recs[j];
    float w = __int_as_float(rec.y);
    unsigned hv = *(const unsigned*)(hB + (size_t)rec.x * 128 + 2 * lane);
    c0 += fmaxf(bflo(hv) + w * wl.x + bl.x, 0.0f);
    c1 += fmaxf(bfhi(hv) + w * wl.y + bl.y, 0.0f);
  }
  unsigned hself = *(const unsigned*)(hB + (size_t)node * 128 + 2 * lane);
  float z0v = bflo(hself) + c0, z1v = bfhi(hself) + c1;
  *(unsigned*)(zB + (size_t)node * 128 + 2 * lane) = pack2(z0v, z1v);
}

// ---------------- node MLP chain + post ----------------
extern "C" __global__ void __launch_bounds__(256, 2) node_kernel(
    const unsigned short* __restrict__ zB, const unsigned short* __restrict__ hB,
    const unsigned short* __restrict__ wbf,
    const float* __restrict__ mb0, const float* __restrict__ mb1, const float* __restrict__ mb2,
    const float* __restrict__ qb0, const float* __restrict__ qb1,
    float* out, int N) {
  __shared__ unsigned short aS[128 * LDP];
  __shared__ unsigned short wS[128 * LDP];
  const int tid = threadIdx.x, lane = tid & 63, wave = tid >> 6;
  const int l15 = lane & 15, lg = lane >> 4;
  const int wr = wave >> 1, wc = wave & 1;
  const int chBase = 64 * wr, nodeBase = 64 * wc;
  const int nb = blockIdx.x * 128;

  // stage z tile (bf16 copy; clamp OOB rows)
  for (int i = tid; i < 128 * 16; i += 256) {
    int r = i >> 4, q = i & 15;
    int node = nb + r; node = node < N ? node : N - 1;
    *(uint4*)(aS + r * LDP + q * 8) = *(const uint4*)(zB + (size_t)node * 128 + q * 8);
  }
  stage_bf(wbf, wS, 128, tid);            // mw0
  __syncthreads();

  f32x4 acc[4][4];

  zero_acc<4, 4>(acc);
  wave_gemm<4, 4, 4, LDP>(wS, aS, chBase, nodeBase, acc, lane);
  __syncthreads();
  write_act_lds_T<0>(acc, mb0, aS, chBase, nodeBase, l15, lg);
  stage_bf(wbf + 16384, wS, 128, tid);    // mw1
  __syncthreads();

  zero_acc<4, 4>(acc);
  wave_gemm<4, 4, 4, LDP>(wS, aS, chBase, nodeBase, acc, lane);
  __syncthreads();
  write_act_lds_T<0>(acc, mb1, aS, chBase, nodeBase, l15, lg);
  stage_bf(wbf + 32768, wS, 128, tid);    // mw2
  __syncthreads();

  zero_acc<4, 4>(acc);
  wave_gemm<4, 4, 4, LDP>(wS, aS, chBase, nodeBase, acc, lane);
  __syncthreads();
  write_act_lds_T<1>(acc, mb2, aS, chBase, nodeBase, l15, lg);
  stage_bf(wbf + 49152, wS, 128, tid);    // qw0a
  __syncthreads();

  zero_acc<4, 4>(acc);
  wave_gemm<4, 4, 4, LDP>(wS, aS, chBase, nodeBase, acc, lane);
  __syncthreads();
  // overwrite aS with the h tile; accumulate qw0b @ h^T
  for (int i = tid; i < 128 * 16; i += 256) {
    int r = i >> 4, q = i & 15;
    int node = nb + r; node = node < N ? node : N - 1;
    *(uint4*)(aS + r * LDP + q * 8) = *(const uint4*)(hB + (size_t)node * 128 + q * 8);
  }
  stage_bf(wbf + 65536, wS, 128, tid);    // qw0b
  __syncthreads();
  wave_gemm<4, 4, 4, LDP>(wS, aS, chBase, nodeBase, acc, lane);
  __syncthreads();
  write_act_lds_T<0>(acc, qb0, aS, chBase, nodeBase, l15, lg);  // p
  stage_bf(wbf + 81920, wS, 64, tid);     // qw1 (64 rows)
  __syncthreads();

  // post layer 1: [128] -> 64, tanh, float4 global stores
  f32x4 acc2[2][4];
  zero_acc<2, 4>(acc2);
  wave_gemm<2, 4, 4, LDP>(wS, aS, 32 * wr, nodeBase, acc2, lane);
  #pragma unroll
  for (int mf = 0; mf < 2; ++mf) {
    const int ch4 = 32 * wr + 16 * mf + 4 * lg;
    const float4 bv = *(const float4*)(qb1 + ch4);
    #pragma unroll
    for (int nf = 0; nf < 4; ++nf) {
      const int node = nb + nodeBase + 16 * nf + l15;
      if (node < N) {
        float4 o;
        o.x = tanh_fast(acc2[mf][nf][0] + bv.x);
        o.y = tanh_fast(acc2[mf][nf][1] + bv.y);
        o.z = tanh_fast(acc2[mf][nf][2] + bv.z);
        o.w = tanh_fast(acc2[mf][nf][3] + bv.w);
        *(float4*)(out + (size_t)node * 64 + ch4) = o;
      }
    }
  }
}

extern "C" void kernel_launch(void* const* d_in, const int* in_sizes, int n_in,
                              void* d_out, int out_size, void* d_ws, size_t ws_size,
                              hipStream_t stream) {
  const float* x   = (const float*)d_in[0];
  const int*   ei  = (const int*)d_in[1];
  const float* ew  = (const float*)d_in[2];
  const float* pw0 = (const float*)d_in[3];
  const float* pb0 = (const float*)d_in[4];
  const float* pw1 = (const float*)d_in[5];
  const float* pb1 = (const float*)d_in[6];
  const float* elw = (const float*)d_in[7];
  const float* elb = (const float*)d_in[8];
  const float* mw0 = (const float*)d_in[9];
  const float* mb0 = (const float*)d_in[10];
  const float* mw1 = (const float*)d_in[11];
  const float* mb1 = (const float*)d_in[12];
  const float* mw2 = (const float*)d_in[13];
  const float* mb2 = (const float*)d_in[14];
  const float* qw0 = (const float*)d_in[15];
  const float* qb0 = (const float*)d_in[16];
  const float* qw1 = (const float*)d_in[17];
  const float* qb1 = (const float*)d_in[18];
  float* out = (float*)d_out;

  const int N = in_sizes[0] / 16;
  const int E = in_sizes[1] / 2;

  // workspace carve-up (256B aligned)
  char* p = (char*)d_ws;
  auto alloc = [&](size_t bytes) { char* r = p; p += (bytes + 255) & ~(size_t)255; return r; };
  const size_t hB_bytes = (size_t)N * 128 * 2;

  unsigned short* zB   = (unsigned short*)alloc(hB_bytes);
  int2*           recs = (int2*)alloc((size_t)E * 8);
  int*            deg  = (int*)alloc((size_t)N * 4);
  int*            offs = (int*)alloc((size_t)N * 4);
  int*            cur  = (int*)alloc((size_t)N * 4);
  int*            part = (int*)alloc(256 * 4);
  int*            basearr = (int*)alloc(256 * 4);
  unsigned short* wbf  = (unsigned short*)alloc(90112 * 2);

  unsigned short* hB;
  if ((size_t)(p - (char*)d_ws) + hB_bytes <= ws_size) {
    hB = (unsigned short*)alloc(hB_bytes);
  } else {
    // alias output: N*64 f32 == N*128 bf16; node_kernel reads own h rows before writing own out rows
    hB = (unsigned short*)d_out;
  }

  const int nblk  = (N + 127) / 128;
  const int nb1   = (N + 2047) / 2048;   // scan blocks (<=64 for N<=131072)
  const int eblk  = (E + 255) / 256;
  const int wconv_threads = (N > 22528) ? N : 22528;

  wconv_kernel<<<dim3((wconv_threads + 255) / 256), dim3(256), 0, stream>>>(
      mw0, mw1, mw2, qw0, qw1, wbf, deg, N);
  prep_kernel<<<dim3(nblk), dim3(256), 0, stream>>>(x, pw0, pb0, pw1, pb1, ei, deg, E, hB, N);
  scan_partials_kernel<<<dim3(nb1), dim3(256), 0, stream>>>(deg, part, N);
  scan_base_kernel<<<dim3(1), dim3(64), 0, stream>>>(part, basearr, nb1);
  scan_apply_kernel<<<dim3(nb1), dim3(256), 0, stream>>>(deg, basearr, offs, cur, N);
  scatter_kernel<<<dim3(eblk), dim3(256), 0, stream>>>(ei, ew, cur, recs, E);
  agg_kernel<<<dim3((N + 3) / 4), dim3(256), 0, stream>>>(offs, cur, recs, elw, elb, hB, zB, N);
  node_kernel<<<dim3(nblk), dim3(256), 0, stream>>>(zB, hB, wbf, mb0, mb1, mb2, qb0, qb1, out, N);
}